// Round 2
// baseline (658.821 us; speedup 1.0000x reference)
//
#include <hip/hip_runtime.h>
#include <hip/hip_bf16.h>

#define U_CNT 100000
#define I_CNT 50000
#define N_CNT 150000   // U + I
#define K_DIM 64
#define E_CNT 500000
#define F_DIM 64
#define N_LAYERS 3
#define B_CNT 100000
#define NBLK_SCAN ((N_CNT + 255) / 256)   // 586
#define EP_TILES (E_CNT / 16)             // 31250 (exact)
#define EP_BLOCKS 2048

typedef __hip_bfloat16 bf16;
typedef __attribute__((ext_vector_type(8))) short short8;
typedef __attribute__((ext_vector_type(8))) unsigned short u16x8;
typedef __attribute__((ext_vector_type(4))) float f32x4;

__device__ __forceinline__ float u2f(unsigned short u) {
    return __uint_as_float(((unsigned)u) << 16);
}
__device__ __forceinline__ unsigned short f2u(float x) {
    bf16 h = __float2bfloat16(x);           // RNE
    return *reinterpret_cast<unsigned short*>(&h);
}

// --- int degree count over both endpoints -----------------------------------
__global__ __launch_bounds__(256) void cnt_kernel(const int* __restrict__ rows,
                                                  const int* __restrict__ cols,
                                                  int* __restrict__ cnt) {
    int e = blockIdx.x * blockDim.x + threadIdx.x;
    if (e < E_CNT) {
        atomicAdd(&cnt[rows[e]], 1);
        atomicAdd(&cnt[cols[e]], 1);
    }
}

// --- dinv[n] = deg>0 ? rsqrt(deg) : 0 ---------------------------------------
__global__ __launch_bounds__(256) void dinv_kernel(const int* __restrict__ cnt,
                                                   float* __restrict__ dinv) {
    int n = blockIdx.x * blockDim.x + threadIdx.x;
    if (n < N_CNT) {
        int c = cnt[n];
        dinv[n] = (c > 0) ? rsqrtf((float)c) : 0.0f;
    }
}

// --- hierarchical exclusive scan --------------------------------------------
__global__ __launch_bounds__(256) void scanA_kernel(const int* __restrict__ cnt,
                                                    int* __restrict__ bsum) {
    __shared__ int sd[256];
    int tid = threadIdx.x;
    int i = blockIdx.x * 256 + tid;
    sd[tid] = (i < N_CNT) ? cnt[i] : 0;
    __syncthreads();
    for (int off = 128; off > 0; off >>= 1) {
        if (tid < off) sd[tid] += sd[tid + off];
        __syncthreads();
    }
    if (tid == 0) bsum[blockIdx.x] = sd[0];
}

__global__ __launch_bounds__(1024) void scanB_kernel(const int* __restrict__ bsum,
                                                     int* __restrict__ boff) {
    __shared__ int sd[1024];
    int tid = threadIdx.x;
    int v = (tid < NBLK_SCAN) ? bsum[tid] : 0;
    sd[tid] = v;
    __syncthreads();
    for (int off = 1; off < 1024; off <<= 1) {
        int t = 0;
        if (tid >= off) t = sd[tid - off];
        __syncthreads();
        if (tid >= off) sd[tid] += t;
        __syncthreads();
    }
    if (tid < NBLK_SCAN) boff[tid] = sd[tid] - v;
}

__global__ __launch_bounds__(256) void scanC_kernel(const int* __restrict__ cnt,
                                                    const int* __restrict__ boff,
                                                    int* __restrict__ offs,
                                                    int* __restrict__ cursor) {
    __shared__ int sd[256];
    int tid = threadIdx.x;
    int i = blockIdx.x * 256 + tid;
    int v = (i < N_CNT) ? cnt[i] : 0;
    sd[tid] = v;
    __syncthreads();
    for (int off = 1; off < 256; off <<= 1) {
        int t = 0;
        if (tid >= off) t = sd[tid - off];
        __syncthreads();
        if (tid >= off) sd[tid] += t;
        __syncthreads();
    }
    if (i < N_CNT) {
        int ex = boff[blockIdx.x] + sd[tid] - v;
        offs[i] = ex;
        cursor[i] = ex;
    }
    if (blockIdx.x == 0 && tid == 0) offs[N_CNT] = 2 * E_CNT;
}

// --- scatter directed edges into CSR slots, 8B packed records ---------------
// rec = { src byte-offset (src*128), w bits }. Also records the CSR position
// of each edge per direction (dposA: row->col, dposB: col->row) so ep_kernel
// can write epw directly in directed CSR order (making prop's epw reads
// fully sequential).
__global__ __launch_bounds__(256) void scatter_kernel(const int* __restrict__ rows,
                                                      const int* __restrict__ cols,
                                                      const float* __restrict__ dinv,
                                                      int* __restrict__ cursor,
                                                      int2* __restrict__ erec,
                                                      int* __restrict__ dposA,
                                                      int* __restrict__ dposB) {
    int d = blockIdx.x * blockDim.x + threadIdx.x;
    if (d >= 2 * E_CNT) return;
    int eid = (d < E_CNT) ? d : d - E_CNT;
    int src = (d < E_CNT) ? rows[eid] : cols[eid];
    int dst = (d < E_CNT) ? cols[eid] : rows[eid];
    int pos = atomicAdd(&cursor[dst], 1);
    int2 rec;
    rec.x = src << 7;                 // src * K_DIM * sizeof(bf16)
    rec.y = __float_as_int(dinv[src] * dinv[dst]);
    erec[pos] = rec;
    if (d < E_CNT) dposA[eid] = pos;
    else           dposB[eid] = pos;
}

// --- edge projection via MFMA: epw_dir = (ef @ W + b) * nrm, bf16 -----------
// 16-edge x 64-col tiles; K=F=64 as 2 mfma_f32_16x16x32_bf16 steps.
// The result tile is staged in LDS (row-major, padded), then written as 16B
// chunks to BOTH directed CSR positions of each edge (norm is symmetric, so
// the value is identical for both directions). This makes the per-layer prop
// reads of epw_dir perfectly sequential.
__global__ __launch_bounds__(256) void ep_kernel(const float* __restrict__ ef,
                                                 const float* __restrict__ W,
                                                 const float* __restrict__ bias,
                                                 const int* __restrict__ rows,
                                                 const int* __restrict__ cols,
                                                 const float* __restrict__ dinv,
                                                 const int* __restrict__ dposA,
                                                 const int* __restrict__ dposB,
                                                 bf16* __restrict__ epw_dir) {
    __shared__ unsigned short tile[4][16][72];   // +8 pad: 4-way max on 2B writes, 16B-aligned rows
    int lane = threadIdx.x & 63;
    int wv = threadIdx.x >> 6;
    int m15 = lane & 15;
    int quad = lane >> 4;

    short8 bfrag[2][4];
    #pragma unroll
    for (int s = 0; s < 2; s++) {
        #pragma unroll
        for (int t = 0; t < 4; t++) {
            short8 b;
            #pragma unroll
            for (int j = 0; j < 8; j++) {
                int f = s * 32 + quad * 8 + j;
                b[j] = (short)f2u(W[f * K_DIM + t * 16 + m15]);
            }
            bfrag[s][t] = b;
        }
    }
    float bv[4];
    #pragma unroll
    for (int t = 0; t < 4; t++) bv[t] = bias[t * 16 + m15];

    // chunk assignment for the write-out phase: 16 rows x 8 chunks = 128
    int c0 = lane;
    int c1 = lane + 64;
    int row0 = c0 >> 3, cq0 = c0 & 7;
    int row1 = c1 >> 3, cq1 = c1 & 7;

    for (int tb = blockIdx.x * 4 + wv; tb < EP_TILES; tb += EP_BLOCKS * 4) {
        int e0 = tb * 16;
        float wlane = 0.0f;
        if (lane < 16) {
            int e = e0 + lane;
            wlane = dinv[rows[e]] * dinv[cols[e]];
        }
        float wrow[4];
        #pragma unroll
        for (int r = 0; r < 4; r++) wrow[r] = __shfl(wlane, quad * 4 + r, 64);

        short8 afrag[2];
        #pragma unroll
        for (int s = 0; s < 2; s++) {
            const float* src = ef + (size_t)(e0 + m15) * F_DIM + s * 32 + quad * 8;
            float4 lo = *(const float4*)src;
            float4 hi = *(const float4*)(src + 4);
            short8 a;
            a[0] = (short)f2u(lo.x); a[1] = (short)f2u(lo.y);
            a[2] = (short)f2u(lo.z); a[3] = (short)f2u(lo.w);
            a[4] = (short)f2u(hi.x); a[5] = (short)f2u(hi.y);
            a[6] = (short)f2u(hi.z); a[7] = (short)f2u(hi.w);
            afrag[s] = a;
        }

        f32x4 acc[4];
        #pragma unroll
        for (int t = 0; t < 4; t++) acc[t] = (f32x4){0.0f, 0.0f, 0.0f, 0.0f};
        #pragma unroll
        for (int s = 0; s < 2; s++) {
            #pragma unroll
            for (int t = 0; t < 4; t++) {
                acc[t] = __builtin_amdgcn_mfma_f32_16x16x32_bf16(
                    afrag[s], bfrag[s][t], acc[t], 0, 0, 0);
            }
        }
        // stage tile in LDS (wave-local: no barrier needed, lockstep wave)
        #pragma unroll
        for (int t = 0; t < 4; t++) {
            #pragma unroll
            for (int r = 0; r < 4; r++) {
                float v = (acc[t][r] + bv[t]) * wrow[r];
                tile[wv][quad * 4 + r][t * 16 + m15] = f2u(v);
            }
        }
        // write both directed positions, 16B chunks
        u16x8 v0 = *(const u16x8*)&tile[wv][row0][cq0 * 8];
        u16x8 v1 = *(const u16x8*)&tile[wv][row1][cq1 * 8];
        int pA0 = dposA[e0 + row0];
        int pA1 = dposA[e0 + row1];
        int pB0 = dposB[e0 + row0];
        int pB1 = dposB[e0 + row1];
        *(u16x8*)((char*)epw_dir + ((size_t)pA0 << 7) + (cq0 << 4)) = v0;
        *(u16x8*)((char*)epw_dir + ((size_t)pA1 << 7) + (cq1 << 4)) = v1;
        *(u16x8*)((char*)epw_dir + ((size_t)pB0 << 7) + (cq0 << 4)) = v0;
        *(u16x8*)((char*)epw_dir + ((size_t)pB1 << 7) + (cq1 << 4)) = v1;
    }
}

// --- init bf16 tables, vectorized -------------------------------------------
__global__ __launch_bounds__(256) void init_kernel(const float4* __restrict__ Gu,
                                                   const float4* __restrict__ Gi,
                                                   const float4* __restrict__ Gut,
                                                   const float4* __restrict__ Git,
                                                   ushort4* __restrict__ C,
                                                   ushort4* __restrict__ T) {
    int idx = blockIdx.x * blockDim.x + threadIdx.x;
    const int UK4 = U_CNT * K_DIM / 4;
    const int NK4 = N_CNT * K_DIM / 4;
    if (idx >= NK4) return;
    float4 c = (idx < UK4) ? Gu[idx] : Gi[idx - UK4];
    float4 t = (idx < UK4) ? Gut[idx] : Git[idx - UK4];
    ushort4 co, to;
    co.x = f2u(c.x); co.y = f2u(c.y); co.z = f2u(c.z); co.w = f2u(c.w);
    to.x = f2u(t.x); to.y = f2u(t.y); to.z = f2u(t.z); to.w = f2u(t.w);
    C[idx] = co;
    T[idx] = to;
}

// --- one propagation layer: 8 edges per iteration ---------------------------
// Wave per destination node; sub = lane>>3 edge slot, q = lane&7 = 16B chunk.
// Random gathers: Cin/Tin rows (2 x 128B per edge). epw_dir is read
// SEQUENTIALLY (positions [p0,p1) are contiguous for this node), eliminating
// a third of the random-miss traffic that capped the previous version.
__global__ __launch_bounds__(256) void prop_kernel(const int* __restrict__ offs,
                                                   const int2* __restrict__ erec,
                                                   const bf16* __restrict__ epw_dir,
                                                   const bf16* __restrict__ Cin,
                                                   const bf16* __restrict__ Tin,
                                                   bf16* __restrict__ Cout,
                                                   bf16* __restrict__ Tout) {
    int gt = blockIdx.x * blockDim.x + threadIdx.x;
    int n = gt >> 6;
    if (n >= N_CNT) return;
    int lane = threadIdx.x & 63;
    int sub = lane >> 3;
    int q = lane & 7;
    int p0 = offs[n];
    int p1 = offs[n + 1];
    const char* cbase = (const char*)Cin + (q << 4);
    const char* tbase = (const char*)Tin + (q << 4);
    const char* ebase = (const char*)epw_dir + (q << 4);
    float accC[8] = {0.0f, 0.0f, 0.0f, 0.0f, 0.0f, 0.0f, 0.0f, 0.0f};
    float accT[8] = {0.0f, 0.0f, 0.0f, 0.0f, 0.0f, 0.0f, 0.0f, 0.0f};

    int p = p0 + sub;
    int2 r = {0, 0};
    if (p < p1) r = erec[p];
    while (p < p1) {
        u16x8 cv = *(const u16x8*)(cbase + r.x);
        u16x8 tv = *(const u16x8*)(tbase + r.x);
        u16x8 ev = *(const u16x8*)(ebase + ((size_t)p << 7));   // sequential
        float w = __int_as_float(r.y);
        int pn = p + 8;
        if (pn < p1) r = erec[pn];      // prefetch next record under gather wait
        #pragma unroll
        for (int j = 0; j < 8; j++) {
            accC[j] = fmaf(w, u2f(cv[j]), accC[j]);
            accT[j] = fmaf(u2f(ev[j]), u2f(tv[j]), accT[j]);
        }
        p = pn;
    }
    // reduce across the 8 edge slots (sub): lanes sub*8+q -> lane q
    #pragma unroll
    for (int j = 0; j < 8; j++) {
        accC[j] += __shfl_down(accC[j], 32, 64);
        accT[j] += __shfl_down(accT[j], 32, 64);
        accC[j] += __shfl_down(accC[j], 16, 64);
        accT[j] += __shfl_down(accT[j], 16, 64);
        accC[j] += __shfl_down(accC[j], 8, 64);
        accT[j] += __shfl_down(accT[j], 8, 64);
    }
    if (lane < 8) {
        u16x8 oc, ot;
        #pragma unroll
        for (int j = 0; j < 8; j++) {
            oc[j] = f2u(accC[j]);
            ot[j] = f2u(accT[j]);
        }
        *(u16x8*)((char*)Cout + ((size_t)n << 7) + (q << 4)) = oc;
        *(u16x8*)((char*)Tout + ((size_t)n << 7) + (q << 4)) = ot;
    }
}

// --- scoring: wave per query, 64-lane shuffle reduction ---------------------
__global__ __launch_bounds__(256) void score_kernel(const int* __restrict__ users,
                                                    const int* __restrict__ items,
                                                    const bf16* __restrict__ C,
                                                    const bf16* __restrict__ T,
                                                    const float* __restrict__ Bu,
                                                    const float* __restrict__ Bi,
                                                    const float* __restrict__ But,
                                                    const float* __restrict__ Bit,
                                                    const float* __restrict__ Mu,
                                                    float* __restrict__ out) {
    int gt = blockIdx.x * blockDim.x + threadIdx.x;
    int b = gt >> 6;
    int k = threadIdx.x & 63;
    if (b >= B_CNT) return;
    int u = users[b];
    int it = items[b];
    size_t ui = (size_t)u * K_DIM + k;
    size_t ii = (size_t)(U_CNT + it) * K_DIM + k;
    float v = __bfloat162float(C[ui]) * __bfloat162float(C[ii])
            + __bfloat162float(T[ui]) * __bfloat162float(T[ii]);
    #pragma unroll
    for (int off = 32; off > 0; off >>= 1) {
        v += __shfl_down(v, off, 64);
    }
    if (k == 0) {
        v += Bu[u] + Bi[it] + But[u] + Bit[it] + Mu[0];
        out[b] = v;
    }
}

extern "C" void kernel_launch(void* const* d_in, const int* in_sizes, int n_in,
                              void* d_out, int out_size, void* d_ws, size_t ws_size,
                              hipStream_t stream) {
    const float* Gu   = (const float*)d_in[0];
    const float* Gi   = (const float*)d_in[1];
    const float* Gut  = (const float*)d_in[2];
    const float* Git  = (const float*)d_in[3];
    const float* Bu   = (const float*)d_in[4];
    const float* Bi   = (const float*)d_in[5];
    const float* But  = (const float*)d_in[6];
    const float* Bit  = (const float*)d_in[7];
    const float* Mu   = (const float*)d_in[8];
    const float* W    = (const float*)d_in[9];
    const float* bpj  = (const float*)d_in[10];
    const float* ef   = (const float*)d_in[11];
    const int* rows   = (const int*)d_in[12];
    const int* cols   = (const int*)d_in[13];
    const int* users  = (const int*)d_in[14];
    const int* items  = (const int*)d_in[15];
    float* out = (float*)d_out;

    const size_t NK = (size_t)N_CNT * K_DIM;
    const size_t EK2 = (size_t)(2 * E_CNT) * K_DIM;

    char* wp = (char*)d_ws;
    auto alloc = [&](size_t bytes) {
        char* r = wp;
        wp += (bytes + 255) & ~(size_t)255;
        return r;
    };
    bf16* epw_dir = (bf16*)alloc(EK2 * sizeof(bf16));            // 128 MB
    bf16* C0      = (bf16*)alloc(NK * sizeof(bf16));             // 19.2 MB
    bf16* C1      = (bf16*)alloc(NK * sizeof(bf16));
    bf16* T0      = (bf16*)alloc(NK * sizeof(bf16));
    bf16* T1      = (bf16*)alloc(NK * sizeof(bf16));
    float* dinv   = (float*)alloc(N_CNT * sizeof(float));
    int2* erec    = (int2*)alloc((size_t)(2 * E_CNT + 8) * sizeof(int2)); // 8 MB
    int* dposA    = (int*)alloc(E_CNT * sizeof(int));            // 2 MB
    int* dposB    = (int*)alloc(E_CNT * sizeof(int));            // 2 MB
    int* cnt      = (int*)alloc(N_CNT * sizeof(int));
    int* offs     = (int*)alloc((N_CNT + 1) * sizeof(int));
    int* cursor   = (int*)alloc(N_CNT * sizeof(int));
    int* bsum     = (int*)alloc(NBLK_SCAN * sizeof(int));
    int* boff     = (int*)alloc(NBLK_SCAN * sizeof(int));

    hipMemsetAsync(cnt, 0, N_CNT * sizeof(int), stream);
    cnt_kernel<<<(E_CNT + 255) / 256, 256, 0, stream>>>(rows, cols, cnt);
    dinv_kernel<<<(N_CNT + 255) / 256, 256, 0, stream>>>(cnt, dinv);
    scanA_kernel<<<NBLK_SCAN, 256, 0, stream>>>(cnt, bsum);
    scanB_kernel<<<1, 1024, 0, stream>>>(bsum, boff);
    scanC_kernel<<<NBLK_SCAN, 256, 0, stream>>>(cnt, boff, offs, cursor);
    scatter_kernel<<<(2 * E_CNT + 255) / 256, 256, 0, stream>>>(
        rows, cols, dinv, cursor, erec, dposA, dposB);
    ep_kernel<<<EP_BLOCKS, 256, 0, stream>>>(ef, W, bpj, rows, cols, dinv,
                                             dposA, dposB, epw_dir);
    init_kernel<<<((int)(NK / 4) + 255) / 256, 256, 0, stream>>>(
        (const float4*)Gu, (const float4*)Gi, (const float4*)Gut, (const float4*)Git,
        (ushort4*)C0, (ushort4*)T0);

    bf16* Cs[2] = {C0, C1};
    bf16* Ts[2] = {T0, T1};
    int cur = 0;
    for (int l = 0; l < N_LAYERS; l++) {
        prop_kernel<<<(N_CNT * 64 + 255) / 256, 256, 0, stream>>>(
            offs, erec, epw_dir, Cs[cur], Ts[cur], Cs[1 - cur], Ts[1 - cur]);
        cur = 1 - cur;
    }

    score_kernel<<<(B_CNT * 64 + 255) / 256, 256, 0, stream>>>(
        users, items, Cs[cur], Ts[cur], Bu, Bi, But, Bit, Mu, out);
}

// Round 3
// 594.761 us; speedup vs baseline: 1.1077x; 1.1077x over previous
//
#include <hip/hip_runtime.h>
#include <hip/hip_bf16.h>

#define U_CNT 100000
#define I_CNT 50000
#define N_CNT 150000   // U + I
#define K_DIM 64
#define E_CNT 500000
#define F_DIM 64
#define N_LAYERS 3
#define B_CNT 100000
#define NBLK_SCAN ((N_CNT + 255) / 256)   // 586
#define EP_TILES (E_CNT / 16)             // 31250 (exact)
#define EP_BLOCKS 2048

typedef __hip_bfloat16 bf16;
typedef __attribute__((ext_vector_type(8))) short short8;
typedef __attribute__((ext_vector_type(8))) unsigned short u16x8;
typedef __attribute__((ext_vector_type(4))) float f32x4;
typedef __attribute__((ext_vector_type(2))) float f32x2;

__device__ __forceinline__ float u2f(unsigned short u) {
    return __uint_as_float(((unsigned)u) << 16);
}
__device__ __forceinline__ unsigned short f2u(float x) {
    bf16 h = __float2bfloat16(x);           // RNE
    return *reinterpret_cast<unsigned short*>(&h);
}

// --- int degree count over both endpoints -----------------------------------
__global__ __launch_bounds__(256) void cnt_kernel(const int* __restrict__ rows,
                                                  const int* __restrict__ cols,
                                                  int* __restrict__ cnt) {
    int e = blockIdx.x * blockDim.x + threadIdx.x;
    if (e < E_CNT) {
        atomicAdd(&cnt[rows[e]], 1);
        atomicAdd(&cnt[cols[e]], 1);
    }
}

// --- dinv[n] = deg>0 ? rsqrt(deg) : 0 ---------------------------------------
__global__ __launch_bounds__(256) void dinv_kernel(const int* __restrict__ cnt,
                                                   float* __restrict__ dinv) {
    int n = blockIdx.x * blockDim.x + threadIdx.x;
    if (n < N_CNT) {
        int c = cnt[n];
        dinv[n] = (c > 0) ? rsqrtf((float)c) : 0.0f;
    }
}

// --- hierarchical exclusive scan --------------------------------------------
__global__ __launch_bounds__(256) void scanA_kernel(const int* __restrict__ cnt,
                                                    int* __restrict__ bsum) {
    __shared__ int sd[256];
    int tid = threadIdx.x;
    int i = blockIdx.x * 256 + tid;
    sd[tid] = (i < N_CNT) ? cnt[i] : 0;
    __syncthreads();
    for (int off = 128; off > 0; off >>= 1) {
        if (tid < off) sd[tid] += sd[tid + off];
        __syncthreads();
    }
    if (tid == 0) bsum[blockIdx.x] = sd[0];
}

__global__ __launch_bounds__(1024) void scanB_kernel(const int* __restrict__ bsum,
                                                     int* __restrict__ boff) {
    __shared__ int sd[1024];
    int tid = threadIdx.x;
    int v = (tid < NBLK_SCAN) ? bsum[tid] : 0;
    sd[tid] = v;
    __syncthreads();
    for (int off = 1; off < 1024; off <<= 1) {
        int t = 0;
        if (tid >= off) t = sd[tid - off];
        __syncthreads();
        if (tid >= off) sd[tid] += t;
        __syncthreads();
    }
    if (tid < NBLK_SCAN) boff[tid] = sd[tid] - v;
}

__global__ __launch_bounds__(256) void scanC_kernel(const int* __restrict__ cnt,
                                                    const int* __restrict__ boff,
                                                    int* __restrict__ offs,
                                                    int* __restrict__ cursor) {
    __shared__ int sd[256];
    int tid = threadIdx.x;
    int i = blockIdx.x * 256 + tid;
    int v = (i < N_CNT) ? cnt[i] : 0;
    sd[tid] = v;
    __syncthreads();
    for (int off = 1; off < 256; off <<= 1) {
        int t = 0;
        if (tid >= off) t = sd[tid - off];
        __syncthreads();
        if (tid >= off) sd[tid] += t;
        __syncthreads();
    }
    if (i < N_CNT) {
        int ex = boff[blockIdx.x] + sd[tid] - v;
        offs[i] = ex;
        cursor[i] = ex;
    }
    if (blockIdx.x == 0 && tid == 0) offs[N_CNT] = 2 * E_CNT;
}

// --- scatter directed edges into CSR slots, 16B packed records --------------
// rec = { src*256 (byte off into CT), eid*64 (byte off into fp8 epw), w, 0 }
__global__ __launch_bounds__(256) void scatter_kernel(const int* __restrict__ rows,
                                                      const int* __restrict__ cols,
                                                      const float* __restrict__ dinv,
                                                      int* __restrict__ cursor,
                                                      int4* __restrict__ erec) {
    int d = blockIdx.x * blockDim.x + threadIdx.x;
    if (d >= 2 * E_CNT) return;
    int eid = (d < E_CNT) ? d : d - E_CNT;
    int src = (d < E_CNT) ? rows[eid] : cols[eid];
    int dst = (d < E_CNT) ? cols[eid] : rows[eid];
    int pos = atomicAdd(&cursor[dst], 1);
    int4 rec;
    rec.x = src << 8;                 // src * 256B (interleaved CT row)
    rec.y = eid << 6;                 // eid * 64B (fp8 epw row)
    rec.z = __float_as_int(dinv[src] * dinv[dst]);
    rec.w = 0;
    erec[pos] = rec;
}

// --- edge projection via MFMA: epw = fp8_e4m3((ef @ W + b) * nrm) -----------
// 16-edge x 64-col tiles; K=F=64 as 2 mfma_f32_16x16x32_bf16 steps.
// Output: 64B fp8 per edge, written SEQUENTIALLY (1KB per tile via LDS stage).
// fp8 on the textual channel is numerically invisible in xui (textual shrinks
// ~ep-scale (0.08x) per layer; its contribution is orders below bf16 quantum).
__global__ __launch_bounds__(256) void ep_kernel(const float* __restrict__ ef,
                                                 const float* __restrict__ W,
                                                 const float* __restrict__ bias,
                                                 const int* __restrict__ rows,
                                                 const int* __restrict__ cols,
                                                 const float* __restrict__ dinv,
                                                 unsigned char* __restrict__ epw) {
    __shared__ unsigned char tile[4][1024];   // per-wave 16 edges x 64 fp8
    int lane = threadIdx.x & 63;
    int wv = threadIdx.x >> 6;
    int m15 = lane & 15;
    int quad = lane >> 4;

    short8 bfrag[2][4];
    #pragma unroll
    for (int s = 0; s < 2; s++) {
        #pragma unroll
        for (int t = 0; t < 4; t++) {
            short8 b;
            #pragma unroll
            for (int j = 0; j < 8; j++) {
                int f = s * 32 + quad * 8 + j;
                b[j] = (short)f2u(W[f * K_DIM + t * 16 + m15]);
            }
            bfrag[s][t] = b;
        }
    }
    float bv[4];
    #pragma unroll
    for (int t = 0; t < 4; t++) bv[t] = bias[t * 16 + m15];

    for (int tb = blockIdx.x * 4 + wv; tb < EP_TILES; tb += EP_BLOCKS * 4) {
        int e0 = tb * 16;
        float wlane = 0.0f;
        if (lane < 16) {
            int e = e0 + lane;
            wlane = dinv[rows[e]] * dinv[cols[e]];
        }
        float wrow[4];
        #pragma unroll
        for (int r = 0; r < 4; r++) wrow[r] = __shfl(wlane, quad * 4 + r, 64);

        short8 afrag[2];
        #pragma unroll
        for (int s = 0; s < 2; s++) {
            const float* src = ef + (size_t)(e0 + m15) * F_DIM + s * 32 + quad * 8;
            float4 lo = *(const float4*)src;
            float4 hi = *(const float4*)(src + 4);
            short8 a;
            a[0] = (short)f2u(lo.x); a[1] = (short)f2u(lo.y);
            a[2] = (short)f2u(lo.z); a[3] = (short)f2u(lo.w);
            a[4] = (short)f2u(hi.x); a[5] = (short)f2u(hi.y);
            a[6] = (short)f2u(hi.z); a[7] = (short)f2u(hi.w);
            afrag[s] = a;
        }

        f32x4 acc[4];
        #pragma unroll
        for (int t = 0; t < 4; t++) acc[t] = (f32x4){0.0f, 0.0f, 0.0f, 0.0f};
        #pragma unroll
        for (int s = 0; s < 2; s++) {
            #pragma unroll
            for (int t = 0; t < 4; t++) {
                acc[t] = __builtin_amdgcn_mfma_f32_16x16x32_bf16(
                    afrag[s], bfrag[s][t], acc[t], 0, 0, 0);
            }
        }
        // encode fp8 bytes into LDS (wave-local; DS ops of a wave are ordered)
        #pragma unroll
        for (int t = 0; t < 4; t++) {
            #pragma unroll
            for (int r = 0; r < 4; r++) {
                float v = (acc[t][r] + bv[t]) * wrow[r];
                unsigned pk = __builtin_amdgcn_cvt_pk_fp8_f32(v, v, 0u, false);
                tile[wv][(quad * 4 + r) * 64 + t * 16 + m15] = (unsigned char)(pk & 0xFF);
            }
        }
        // sequential 1KB write-out, 16B per lane
        uint4 vv = *(const uint4*)&tile[wv][lane * 16];
        *(uint4*)(epw + (size_t)tb * 1024 + lane * 16) = vv;
    }
}

// --- init interleaved CT table: [n] = { C row 128B | T row 128B } -----------
__global__ __launch_bounds__(256) void init_kernel(const float* __restrict__ Gu,
                                                   const float* __restrict__ Gi,
                                                   const float* __restrict__ Gut,
                                                   const float* __restrict__ Git,
                                                   bf16* __restrict__ CT) {
    int tid = blockIdx.x * blockDim.x + threadIdx.x;
    const int TOT = N_CNT * 16;            // 16B chunks per node row
    if (tid >= TOT) return;
    int n = tid >> 4;
    int c = tid & 15;
    int co = c & 7;
    const float* src;
    if (c < 8) src = (n < U_CNT) ? Gu + (size_t)n * K_DIM
                                 : Gi + (size_t)(n - U_CNT) * K_DIM;
    else       src = (n < U_CNT) ? Gut + (size_t)n * K_DIM
                                 : Git + (size_t)(n - U_CNT) * K_DIM;
    float4 lo = *(const float4*)(src + co * 8);
    float4 hi = *(const float4*)(src + co * 8 + 4);
    u16x8 o;
    o[0] = f2u(lo.x); o[1] = f2u(lo.y); o[2] = f2u(lo.z); o[3] = f2u(lo.w);
    o[4] = f2u(hi.x); o[5] = f2u(hi.y); o[6] = f2u(hi.z); o[7] = f2u(hi.w);
    *(u16x8*)((char*)CT + ((size_t)n << 8) + (c << 4)) = o;
}

// --- one propagation layer: 4 edges/iter, interleaved CT --------------------
// Wave per destination node. sub = lane>>4 edge slot; q = lane&15 = 16B chunk
// of the 256B CT row (q<8: C half, q>=8: T half). Per edge: ONE contiguous
// 256B CT gather + ONE 64B fp8 epw gather (was 3 random 128B rows).
__global__ __launch_bounds__(256) void prop_kernel(const int* __restrict__ offs,
                                                   const int4* __restrict__ erec,
                                                   const unsigned char* __restrict__ epw,
                                                   const bf16* __restrict__ CTin,
                                                   bf16* __restrict__ CTout) {
    int gt = blockIdx.x * blockDim.x + threadIdx.x;
    int n = gt >> 6;
    if (n >= N_CNT) return;
    int lane = threadIdx.x & 63;
    int sub = lane >> 4;
    int q = lane & 15;
    int p0 = offs[n];
    int p1 = offs[n + 1];
    const char* ctb = (const char*)CTin + (q << 4);
    const char* epb = (const char*)epw + ((q & 7) << 3);
    bool isT = q >= 8;
    float acc[8] = {0.0f, 0.0f, 0.0f, 0.0f, 0.0f, 0.0f, 0.0f, 0.0f};

    int p = p0 + sub;
    int4 r = {0, 0, 0, 0};
    if (p < p1) r = erec[p];
    while (p < p1) {
        u16x8 cv = *(const u16x8*)(ctb + (unsigned)r.x);
        uint2 ew = *(const uint2*)(epb + (unsigned)r.y);
        float w = __int_as_float(r.z);
        int pn = p + 4;
        if (pn < p1) r = erec[pn];      // prefetch next record under gather wait
        f32x2 e01 = __builtin_amdgcn_cvt_pk_f32_fp8(ew.x, false);
        f32x2 e23 = __builtin_amdgcn_cvt_pk_f32_fp8(ew.x, true);
        f32x2 e45 = __builtin_amdgcn_cvt_pk_f32_fp8(ew.y, false);
        f32x2 e67 = __builtin_amdgcn_cvt_pk_f32_fp8(ew.y, true);
        float ev[8] = {e01[0], e01[1], e23[0], e23[1],
                       e45[0], e45[1], e67[0], e67[1]};
        #pragma unroll
        for (int j = 0; j < 8; j++) {
            float f = isT ? ev[j] : w;   // C-lanes ignore decoded garbage-free ev
            acc[j] = fmaf(f, u2f(cv[j]), acc[j]);
        }
        p = pn;
    }
    // reduce across the 4 edge slots (sub): lanes sub*16+q -> lane q
    #pragma unroll
    for (int j = 0; j < 8; j++) {
        acc[j] += __shfl_down(acc[j], 32, 64);
        acc[j] += __shfl_down(acc[j], 16, 64);
    }
    if (lane < 16) {
        u16x8 o;
        #pragma unroll
        for (int j = 0; j < 8; j++) o[j] = f2u(acc[j]);
        *(u16x8*)((char*)CTout + ((size_t)n << 8) + (q << 4)) = o;
    }
}

// --- scoring: wave per query; CT row is 128 elems = C|T, one fused dot ------
__global__ __launch_bounds__(256) void score_kernel(const int* __restrict__ users,
                                                    const int* __restrict__ items,
                                                    const bf16* __restrict__ CT,
                                                    const float* __restrict__ Bu,
                                                    const float* __restrict__ Bi,
                                                    const float* __restrict__ But,
                                                    const float* __restrict__ Bit,
                                                    const float* __restrict__ Mu,
                                                    float* __restrict__ out) {
    int gt = blockIdx.x * blockDim.x + threadIdx.x;
    int b = gt >> 6;
    int k = threadIdx.x & 63;
    if (b >= B_CNT) return;
    int u = users[b];
    int it = items[b];
    ushort2 a = *(const ushort2*)((const char*)CT + ((size_t)u << 8) + (k << 2));
    ushort2 c = *(const ushort2*)((const char*)CT + ((size_t)(U_CNT + it) << 8) + (k << 2));
    float v = u2f(a.x) * u2f(c.x) + u2f(a.y) * u2f(c.y);
    #pragma unroll
    for (int off = 32; off > 0; off >>= 1) {
        v += __shfl_down(v, off, 64);
    }
    if (k == 0) {
        v += Bu[u] + Bi[it] + But[u] + Bit[it] + Mu[0];
        out[b] = v;
    }
}

extern "C" void kernel_launch(void* const* d_in, const int* in_sizes, int n_in,
                              void* d_out, int out_size, void* d_ws, size_t ws_size,
                              hipStream_t stream) {
    const float* Gu   = (const float*)d_in[0];
    const float* Gi   = (const float*)d_in[1];
    const float* Gut  = (const float*)d_in[2];
    const float* Git  = (const float*)d_in[3];
    const float* Bu   = (const float*)d_in[4];
    const float* Bi   = (const float*)d_in[5];
    const float* But  = (const float*)d_in[6];
    const float* Bit  = (const float*)d_in[7];
    const float* Mu   = (const float*)d_in[8];
    const float* W    = (const float*)d_in[9];
    const float* bpj  = (const float*)d_in[10];
    const float* ef   = (const float*)d_in[11];
    const int* rows   = (const int*)d_in[12];
    const int* cols   = (const int*)d_in[13];
    const int* users  = (const int*)d_in[14];
    const int* items  = (const int*)d_in[15];
    float* out = (float*)d_out;

    const size_t CTB = (size_t)N_CNT * 256;      // interleaved CT bytes

    char* wp = (char*)d_ws;
    auto alloc = [&](size_t bytes) {
        char* r = wp;
        wp += (bytes + 255) & ~(size_t)255;
        return r;
    };
    unsigned char* epw = (unsigned char*)alloc((size_t)E_CNT * 64);  // 32 MB fp8
    bf16* CT0     = (bf16*)alloc(CTB);                               // 38.4 MB
    bf16* CT1     = (bf16*)alloc(CTB);
    float* dinv   = (float*)alloc(N_CNT * sizeof(float));
    int4* erec    = (int4*)alloc((size_t)(2 * E_CNT + 8) * sizeof(int4)); // 16 MB
    int* cnt      = (int*)alloc(N_CNT * sizeof(int));
    int* offs     = (int*)alloc((N_CNT + 1) * sizeof(int));
    int* cursor   = (int*)alloc(N_CNT * sizeof(int));
    int* bsum     = (int*)alloc(NBLK_SCAN * sizeof(int));
    int* boff     = (int*)alloc(NBLK_SCAN * sizeof(int));

    hipMemsetAsync(cnt, 0, N_CNT * sizeof(int), stream);
    cnt_kernel<<<(E_CNT + 255) / 256, 256, 0, stream>>>(rows, cols, cnt);
    dinv_kernel<<<(N_CNT + 255) / 256, 256, 0, stream>>>(cnt, dinv);
    scanA_kernel<<<NBLK_SCAN, 256, 0, stream>>>(cnt, bsum);
    scanB_kernel<<<1, 1024, 0, stream>>>(bsum, boff);
    scanC_kernel<<<NBLK_SCAN, 256, 0, stream>>>(cnt, boff, offs, cursor);
    scatter_kernel<<<(2 * E_CNT + 255) / 256, 256, 0, stream>>>(
        rows, cols, dinv, cursor, erec);
    ep_kernel<<<EP_BLOCKS, 256, 0, stream>>>(ef, W, bpj, rows, cols, dinv, epw);
    init_kernel<<<(N_CNT * 16 + 255) / 256, 256, 0, stream>>>(
        Gu, Gi, Gut, Git, CT0);

    bf16* CTs[2] = {CT0, CT1};
    int cur = 0;
    for (int l = 0; l < N_LAYERS; l++) {
        prop_kernel<<<(N_CNT * 64 + 255) / 256, 256, 0, stream>>>(
            offs, erec, epw, CTs[cur], CTs[1 - cur]);
        cur = 1 - cur;
    }

    score_kernel<<<(B_CNT * 64 + 255) / 256, 256, 0, stream>>>(
        users, items, CTs[cur], Bu, Bi, But, Bit, Mu, out);
}